// Round 10
// baseline (170.047 us; speedup 1.0000x reference)
//
#include <hip/hip_runtime.h>
#include <math.h>

// ---------------------------------------------------------------------------
// FPSANConv2d: out = conv3x3(x, Qt(w)) + b + sigmoid(gate)*(conv3x3(x, Qt(w_child)) + b_child)
// Fused: W_eff = Qt(w) + g*Qt(w_child) (bf16), b_eff = b + g*b_child, ONE conv.
//
// Round 15: split-K over ci (2 halves of 32).
//   Ledger: B-from-global = 67-72us (R8,R14: compiler sinks loads, VGPR 56-60);
//   B-from-LDS = 45-50us (R12,R13). Revert to LDS-B. New structure:
//   block = 256thr/4 waves, wave = 64px x 64oc, ci-half loop:
//    - per tap: 8 ds_read_b128 (4A+4B) -> 16 MFMAs at K=32 single-shot
//      (R13: 12 reads/16 MFMAs; per-CU tap LDS 41k -> 27.6k cy)
//    - A-tile 32,768B + B 4,096B = 36,864B LDS -> 4 blocks/CU: each SIMD
//      hosts waves of 4 DIFFERENT blocks -> barriers no longer lockstep.
//   3-bit XOR swizzle slot=(row^((row>>2)&1))*4 + (c^(px&3)): bijective,
//   mf-stride-invariant (+16px = +1024B), ~2-way banks on all access paths.
// ---------------------------------------------------------------------------

typedef __attribute__((ext_vector_type(8))) short short8;   // 8 bf16 (4 VGPRs)
typedef __attribute__((ext_vector_type(4))) float float4v;  // MFMA C/D frag

__device__ inline unsigned short f2bf(float f) {
  union { float f; unsigned u; } v; v.f = f;
  unsigned u = v.u;
  return (unsigned short)((u + 0x7FFFu + ((u >> 16) & 1u)) >> 16);  // RNE
}

// ---- prep: deterministic redundant reduce + ternary quant + gate combine ----
__global__ __launch_bounds__(256) void prep(
    const float* __restrict__ w, const float* __restrict__ wc,
    const float* __restrict__ b, const float* __restrict__ bc,
    const float* __restrict__ gate,
    unsigned short* __restrict__ wq, float* __restrict__ beff) {
  const int tid = threadIdx.x;
  const float4v* w4 = (const float4v*)w;    // 9216 float4
  const float4v* c4 = (const float4v*)wc;
  double a0 = 0, a1 = 0, a2 = 0, a3 = 0;
  double c0 = 0, c1 = 0, c2 = 0, c3 = 0;
#pragma unroll
  for (int i = 0; i < 36; i += 4) {         // batch: 8 float4 loads in flight
    float4v wa = w4[tid + (i + 0) * 256];
    float4v wb = w4[tid + (i + 1) * 256];
    float4v wcv = w4[tid + (i + 2) * 256];
    float4v wd = w4[tid + (i + 3) * 256];
    float4v xa = c4[tid + (i + 0) * 256];
    float4v xb = c4[tid + (i + 1) * 256];
    float4v xc = c4[tid + (i + 2) * 256];
    float4v xd = c4[tid + (i + 3) * 256];
    a0 += (double)fabsf(wa[0]) + (double)fabsf(wa[1]) + (double)fabsf(wa[2]) + (double)fabsf(wa[3]);
    a1 += (double)fabsf(wb[0]) + (double)fabsf(wb[1]) + (double)fabsf(wb[2]) + (double)fabsf(wb[3]);
    a2 += (double)fabsf(wcv[0]) + (double)fabsf(wcv[1]) + (double)fabsf(wcv[2]) + (double)fabsf(wcv[3]);
    a3 += (double)fabsf(wd[0]) + (double)fabsf(wd[1]) + (double)fabsf(wd[2]) + (double)fabsf(wd[3]);
    c0 += (double)fabsf(xa[0]) + (double)fabsf(xa[1]) + (double)fabsf(xa[2]) + (double)fabsf(xa[3]);
    c1 += (double)fabsf(xb[0]) + (double)fabsf(xb[1]) + (double)fabsf(xb[2]) + (double)fabsf(xb[3]);
    c2 += (double)fabsf(xc[0]) + (double)fabsf(xc[1]) + (double)fabsf(xc[2]) + (double)fabsf(xc[3]);
    c3 += (double)fabsf(xd[0]) + (double)fabsf(xd[1]) + (double)fabsf(xd[2]) + (double)fabsf(xd[3]);
  }
  double a = (a0 + a1) + (a2 + a3);
  double c = (c0 + c1) + (c2 + c3);
#pragma unroll
  for (int off = 32; off > 0; off >>= 1) {
    a += __shfl_down(a, off);
    c += __shfl_down(c, off);
  }
  __shared__ double sa[4], sc[4];
  const int wv = tid >> 6;
  if ((tid & 63) == 0) { sa[wv] = a; sc[wv] = c; }
  __syncthreads();
  const double ta = (sa[0] + sa[1]) + (sa[2] + sa[3]);
  const double tc = (sc[0] + sc[1]) + (sc[2] + sc[3]);
  const float sw = fmaxf((float)(ta * (1.0 / 36864.0)), 1e-5f);
  const float scl = fmaxf((float)(tc * (1.0 / 36864.0)), 1e-5f);
  const float g = 1.0f / (1.0f + expf(-gate[0]));
  const int idx = blockIdx.x * 256 + tid;  // (tap, oc, ci)
  const int tap = idx >> 12;
  const int oc = (idx >> 6) & 63;
  const int ci = idx & 63;
  const int src = oc * 576 + ci * 9 + tap;  // OIHW flat
  float q1 = fminf(1.f, fmaxf(-1.f, rintf(w[src] / sw))) * sw;
  float q2 = fminf(1.f, fmaxf(-1.f, rintf(wc[src] / scl))) * scl;
  wq[idx] = f2bf(q1 + g * q2);
  if (idx < 64) beff[idx] = b[idx] + g * bc[idx];
}

// ---- conv: split-K implicit GEMM ----
// Block: 256 thr = 4 waves; tile = 2 output rows x 128 px x 64 oc.
// Wave wv: rw = wv>>1 (row), pxh = (wv&1)*64. Wave = 64px x 64oc, acc[4][4].
// ci-half loop (ph=0,1): stage A(4 rows x 128px x 32ci, 32,768B) + B tap0,
//   then 9 taps: {read 4A+4B b128, bar1, prefetch B[t+1] reg, 16 MFMA K=32,
//   write B[t+1], bar2}. LDS 36,864B -> 4 blocks/CU, SIMDs host 4 different
//   blocks -> barriers don't lockstep the CU.
// Swizzle: slot = (row ^ ((row>>2)&1))*4 + (c ^ (px&3)), row = r*128+px-1.
//   Bijective; +16px => +64 slots (swizzle bits unchanged) => uniform mf
//   stride 1024B; pad px=0: base goes negative but every dereferenced
//   address (off0>=1024) is valid & the frag is zeroed; pad px=129: off3=0
//   redirect + zero. B slot analogous on oc.
__global__ __launch_bounds__(256, 4) void conv_fused(
    const float* __restrict__ x, const unsigned short* __restrict__ wq,
    const float* __restrict__ beff, float* __restrict__ out) {
  extern __shared__ __align__(16) char smem[];  // 36,864 B
  char* Abase = smem;                  // 2048 chunks (32,768 B)
  char* Bbase = smem + 32768;          // 256 chunks (4,096 B)

  const int bid = blockIdx.x;          // 1024 blocks
  const int xcd = bid & 7;
  const int u = bid >> 3;              // 0..127
  const int n = xcd * 2 + (u >> 6);    // image
  const int h0 = (u & 63) * 2;         // output rows h0, h0+1
  const int tid = threadIdx.x;
  const int lane = tid & 63;
  const int wv = tid >> 6;             // 0..3
  const int rw = wv >> 1;              // output row within block (0/1)
  const int pxh = (wv & 1) * 64;       // pixel half
  const int ln15 = lane & 15;
  const int lq = lane >> 4;            // 0..3: 16B ci-chunk (8 ci each, 32 ci)

  const float* xn = x + (size_t)n * (64 * 16384);

  // B chunk ownership for staging: thread -> (oc0, c0)
  const int oc0 = tid >> 2;
  const int c0 = tid & 3;
  const int bslot = ((oc0 ^ ((oc0 >> 2) & 1)) << 2) + (c0 ^ (oc0 & 3));
  const unsigned short* bsrc = wq + oc0 * 64 + c0 * 8;  // + tap*4096 + ph*32

  // B read slots (per lane, per qd) -- oc = qd*16 + ln15, chunk lq
  int brd[4];
#pragma unroll
  for (int qd = 0; qd < 4; ++qd) {
    const int oc = qd * 16 + ln15;
    brd[qd] = (((oc ^ ((oc >> 2) & 1)) << 2) + (lq ^ (oc & 3))) << 4;
  }

  const int pxc = tid & 127;           // staged col 0..127 (px = pxc+1)
  const int hi = tid >> 7;             // 0..1 (wave-uniform)

  float4v acc[4][4] = {};              // [mf][qd]

#pragma unroll
  for (int ph = 0; ph < 2; ++ph) {
    // ---- B tap-0 for this ci-half: 1 chunk/thread ----
    const short8 b0 = *(const short8*)(bsrc + ph * 32);

    // ---- A staging: 2 groups x {issue 32 loads, convert+write 4} ----
#pragma unroll
    for (int grp = 0; grp < 2; ++grp) {
      float t[4][8];
#pragma unroll
      for (int j = 0; j < 4; ++j) {    // issue all 32 loads first
        const int k = grp * 8 + j * 2 + hi;  // 0..15
        const int r = k >> 2;          // LDS row 0..3
        const int c = k & 3;           // ci chunk 0..3
        const int h = h0 + r - 1;      // source row, -1..128
        if ((unsigned)h < 128u) {      // wave-uniform
          const float* sp = xn + (ph * 32 + c * 8) * 16384 + h * 128 + pxc;
#pragma unroll
          for (int e = 0; e < 8; ++e) t[j][e] = sp[e * 16384];
        } else {
#pragma unroll
          for (int e = 0; e < 8; ++e) t[j][e] = 0.f;
        }
      }
#pragma unroll
      for (int j = 0; j < 4; ++j) {    // convert + swizzled ds_write
        const int k = grp * 8 + j * 2 + hi;
        const int r = k >> 2;
        const int c = k & 3;
        short8 v;
#pragma unroll
        for (int e = 0; e < 8; ++e) v[e] = (short)f2bf(t[j][e]);
        const int row = r * 128 + pxc;             // px-1
        const int slot = ((row ^ ((row >> 2) & 1)) << 2) + (c ^ ((pxc + 1) & 3));
        *(short8*)(Abase + (slot << 4)) = v;
      }
    }
    *(short8*)(Bbase + (bslot << 4)) = b0;
    __syncthreads();                   // A(ph) + B tap0 visible

#pragma unroll
    for (int tap = 0; tap < 9; ++tap) {
      const int dh = tap / 3;
      const int dw = tap - dh * 3;
      const int r = rw + dh;           // 0..3
      const int pb = pxh + ln15 + dw;  // padded px at mf=0 (0..81)
      const bool p0 = (pb == 0);
      const bool p129 = (pb == 81);
      const int row = r * 128 + pb - 1;            // -1..464
      const int row2 = row ^ ((row >> 2) & 1);     // -1 -> -2 (still consistent)
      const int a0 = ((row2 << 2) + (lq ^ (pb & 3))) << 4;  // may be negative
      const int off0 = p0 ? 1024 : 0;  // every dereferenced addr >= 896: valid
      const int off3 = p129 ? 0 : 3072;

      short8 Ab[4], Bb[4];
      Ab[0] = *(const short8*)(Abase + (a0 + off0));
      Ab[1] = *(const short8*)(Abase + (a0 + 1024));
      Ab[2] = *(const short8*)(Abase + (a0 + 2048));
      Ab[3] = *(const short8*)(Abase + (a0 + off3));
      if (p0) Ab[0] = (short8)0;
      if (p129) Ab[3] = (short8)0;
#pragma unroll
      for (int qd = 0; qd < 4; ++qd)
        Bb[qd] = *(const short8*)(Bbase + brd[qd]);

      __syncthreads();                 // bar1: all waves read B[tap] (&A)

      short8 bnxt;
      if (tap < 8) bnxt = *(const short8*)(bsrc + (tap + 1) * 4096 + ph * 32);

      __builtin_amdgcn_s_setprio(1);
#pragma unroll
      for (int mf = 0; mf < 4; ++mf)
#pragma unroll
        for (int qd = 0; qd < 4; ++qd)
          acc[mf][qd] = __builtin_amdgcn_mfma_f32_16x16x32_bf16(
              Ab[mf], Bb[qd], acc[mf][qd], 0, 0, 0);
      __builtin_amdgcn_s_setprio(0);

      if (tap < 8) {
        *(short8*)(Bbase + (bslot << 4)) = bnxt;  // reads done at bar1
        __syncthreads();               // bar2: B[t+1] visible
      }
    }
    // phase boundary: all waves passed tap8's bar1 (frags in regs) -> A
    // restage for ph=1 is race-free without an extra barrier.
  }

  // ---- epilogue: C/D layout col=lane&15 (oc), row=(lane>>4)*4+reg (pixel) ----
  const int rq = lane >> 4;
  float bias[4];
#pragma unroll
  for (int q = 0; q < 4; ++q) bias[q] = beff[q * 16 + ln15];
#pragma unroll
  for (int mf = 0; mf < 4; ++mf) {
#pragma unroll
    for (int qd = 0; qd < 4; ++qd) {
      float4v v = acc[mf][qd] + bias[qd];
      int oc = qd * 16 + ln15;
      float* op = out + (((n * 64 + oc) * 128 + h0 + rw) * 128 + pxh + mf * 16 + rq * 4);
      *(float4v*)op = v;
    }
  }
}

extern "C" void kernel_launch(void* const* d_in, const int* in_sizes, int n_in,
                              void* d_out, int out_size, void* d_ws, size_t ws_size,
                              hipStream_t stream) {
  const float* x = (const float*)d_in[0];
  const float* w = (const float*)d_in[1];
  const float* b = (const float*)d_in[2];
  const float* wc = (const float*)d_in[3];
  const float* bc = (const float*)d_in[4];
  const float* gate = (const float*)d_in[5];

  // ws: wq bf16[36864]=73728B | beff f32[64] @73728
  unsigned short* wq = (unsigned short*)d_ws;
  float* beff = (float*)((char*)d_ws + 73728);

  prep<<<144, 256, 0, stream>>>(w, wc, b, bc, gate, wq, beff);
  conv_fused<<<1024, 256, 36864, stream>>>(x, wq, beff, (float*)d_out);
}